// Round 5
// baseline (579.657 us; speedup 1.0000x reference)
//
#include <hip/hip_runtime.h>
#include <math.h>

#define KK 9
#define NB 4
#define NC 64
#define NO 64
#define NH 128
#define HP 136
#define NPIX (NH*NH)     /* 16384 */
#define PADPIX (HP*HP)   /* 18496 */
#define NCH 18

/* workspace layout (float offsets) */
#define SZ_FP    (NB*NC*PADPIX)        /* 4,734,976 */
#define O_FPCHW  0
#define O_FPFLAT (O_FPCHW + SZ_FP)
#define O_OFF    (O_FPFLAT + SZ_FP)
#define SZ_OFF   (NB*NCH*NPIX)         /* 1,179,648 */
#define O_STATS  (O_OFF + SZ_OFF)
#define O_WX     (O_STATS + 64)
#define O_WY     (O_WX + KK*64*64)
#define O_R2     (O_WY + KK*64*64)
#define SZ_R     (NB*KK*NPIX)          /* 589,824 */
#define O_R3     (O_R2 + SZ_R)
/* repacked offset weights wr[c][cg6][ky][u3][12]: 64*1944 floats, after r3
   (wr is live only through k_off; r2+r3 double as the half-0 partial array
   pp0, which is dead before k_idx overwrites r2/r3 with indices). */
#define O_WR     (O_R3 + SZ_R)
#define WS_FLOATS (O_WR + 64*1944)     /* ~12.03M floats = 48.1 MB */

__global__ void k_zero(float4* p, int n4) {
    int id = blockIdx.x * 256 + threadIdx.x;
    if (id < n4) p[id] = make_float4(0.f, 0.f, 0.f, 0.f);
}

/* padded layouts of f: LDS-tiled so BOTH writes are coalesced */
__global__ __launch_bounds__(256) void k_pad(const float* __restrict__ f,
                                             float* __restrict__ fpchw,
                                             float* __restrict__ fpflat) {
    __shared__ float tile[64][65];   /* [c][w] */
    const int wt = blockIdx.x, h = blockIdx.y, b = blockIdx.z;
    const int w0 = wt * 64;
    const int tc = threadIdx.x >> 6;   /* 0..3 */
    const int tw = threadIdx.x & 63;
    for (int cc = tc; cc < 64; cc += 4) {
        float v = f[((b * 64 + cc) * 128 + h) * 128 + w0 + tw];
        tile[cc][tw] = v;
        fpchw[((b * 64 + cc) * HP + h + 4) * HP + w0 + tw + 4] = v;
    }
    __syncthreads();
    for (int pp = tc; pp < 64; pp += 4) {
        fpflat[(((b * HP + h + 4) * HP) + w0 + pp + 4) * 64 + tw] = tile[tw][pp];
    }
}

/* transpose main-conv weights to [k][c][o] AND repack offset weights to
   wr[c][cg][ky][u][12] with cg = co/3, u = co%3 (kx padded 9->12). */
__global__ void k_wt(const float* __restrict__ cwx, const float* __restrict__ cwy,
                     const float* __restrict__ offw,
                     float* __restrict__ wx, float* __restrict__ wy,
                     float* __restrict__ wr) {
    int id = blockIdx.x * 256 + threadIdx.x;
    if (id < KK * 64 * 64) {
        int o = id & 63;
        int c = (id >> 6) & 63;
        int k = id >> 12;
        wx[id] = cwx[(o * 64 + c) * 9 + k];
        wy[id] = cwy[(o * 64 + c) * 9 + k];
    }
    if (id < 18 * 64 * 9 * 9) {
        int kx = id % 9;
        int r = id / 9;
        int ky = r % 9; r /= 9;
        int c = r % 64;
        int co = r / 64;
        int cg = co / 3, u = co - cg * 3;
        wr[c * 1944 + cg * 324 + (ky * 3 + u) * 12 + kx] =
            offw[((co * 64 + c) * 9 + ky) * 9 + kx];
    }
}

/* offset conv, NO LDS: input via coalesced global dwordx4 (L1/L2-hot, no
   barriers -> vmcnt pipelining), weights via wave-uniform loads -> s_load
   into SGPRs (lgkmcnt carries only SMEM). 3 co x 4 j per thread, channels
   halved. block 128 thr: tr = t>>4 (8 rows), tjj = t&15 (4-j strips).
   grid = (cg6*jt2, ig16, b*2+half) = 1536 blocks = 12 waves/CU.
   Association identical to round-4 kernel: per-(co,c) fp32 tap chain
   ky->kx, double accumulation over ascending c within each half. */
__global__ __launch_bounds__(128) void k_off(const float* __restrict__ fpchw,
                                             const float* __restrict__ wr,
                                             float* __restrict__ pp0,
                                             float* __restrict__ off) {
    const int cg = blockIdx.x >> 1, jt = blockIdx.x & 1;   /* cg 0..5 */
    const int ig = blockIdx.y;                              /* 0..15 */
    const int b = blockIdx.z >> 1, half = blockIdx.z & 1;
    const int t = threadIdx.x;
    const int tr = t >> 4;            /* 0..7 */
    const int tjj = t & 15;
    const int i = ig * 8 + tr;        /* output row */
    const int j0 = jt * 64 + tjj * 4;
    const int c0 = half * 32, co0 = cg * 3;
    float* pout = half ? off : pp0;

    const float* frow0 = fpchw + ((size_t)(b * 64 + c0) * HP + i) * HP + j0;
    const float* wbase = wr + (size_t)c0 * 1944 + cg * 324;

    double acc[3][4];
#pragma unroll
    for (int u = 0; u < 3; ++u)
#pragma unroll
        for (int jj = 0; jj < 4; ++jj) acc[u][jj] = 0.0;

    for (int c = 0; c < 32; ++c) {
        const float* fr = frow0 + (size_t)c * PADPIX;
        const float* wc = wbase + (size_t)c * 1944;
        float p[3][4];
#pragma unroll
        for (int u = 0; u < 3; ++u)
#pragma unroll
            for (int jj = 0; jj < 4; ++jj) p[u][jj] = 0.f;
#pragma unroll
        for (int ky = 0; ky < 9; ++ky) {
            float4 va = *(const float4*)(fr + ky * HP);
            float4 vb = *(const float4*)(fr + ky * HP + 4);
            float4 vc = *(const float4*)(fr + ky * HP + 8);
            const float v[12] = {va.x, va.y, va.z, va.w, vb.x, vb.y, vb.z, vb.w,
                                 vc.x, vc.y, vc.z, vc.w};
#pragma unroll
            for (int u = 0; u < 3; ++u) {
                const float* wp = wc + (ky * 3 + u) * 12;   /* wave-uniform */
                float4 w0 = *(const float4*)(wp);
                float4 w1 = *(const float4*)(wp + 4);
                float w8 = wp[8];
                const float w[9] = {w0.x, w0.y, w0.z, w0.w,
                                    w1.x, w1.y, w1.z, w1.w, w8};
#pragma unroll
                for (int jj = 0; jj < 4; ++jj) {
                    float pu = p[u][jj];
#pragma unroll
                    for (int kx = 0; kx < 9; ++kx)
                        pu = fmaf(v[kx + jj], w[kx], pu);
                    p[u][jj] = pu;
                }
            }
        }
#pragma unroll
        for (int u = 0; u < 3; ++u)
#pragma unroll
            for (int jj = 0; jj < 4; ++jj) acc[u][jj] += (double)p[u][jj];
    }
#pragma unroll
    for (int u = 0; u < 3; ++u)
#pragma unroll
        for (int jj = 0; jj < 4; ++jj)
            pout[((b * NCH + co0 + u) << 14) + (i << 7) + j0 + jj] =
                (float)acc[u][jj];
}

/* combine halves + bias (write back to off) AND per-channel mean/rsqrt(var) */
__global__ __launch_bounds__(256) void k_stats(float* __restrict__ off,
                                               const float* __restrict__ pp0,
                                               const float* __restrict__ offb,
                                               float* __restrict__ stats) {
    int ch = blockIdx.x, t = threadIdx.x;
    float bias = offb[ch];
    double s = 0.0, ss = 0.0;
    for (int p = t; p < NB * NPIX; p += 256) {
        int b = p >> 14, q = p & 16383;
        int x = ((b * NCH + ch) << 14) + q;
        float v = pp0[x] + off[x] + bias;
        off[x] = v;
        s += (double)v;
        ss += (double)v * (double)v;
    }
    __shared__ double sh1[256], sh2[256];
    sh1[t] = s; sh2[t] = ss;
    __syncthreads();
    for (int st = 128; st > 0; st >>= 1) {
        if (t < st) { sh1[t] += sh1[t + st]; sh2[t] += sh2[t + st]; }
        __syncthreads();
    }
    if (t == 0) {
        double n = (double)(NB * NPIX);
        double m = sh1[0] / n;
        double var = sh2[0] / n - m * m;
        stats[ch] = (float)m;
        stats[NCH + ch] = (float)(1.0 / sqrt(var + 1e-5));
    }
}

/* BN + tanh + cum + floor -> gather row indices (reproduces base-stride bug) */
__global__ __launch_bounds__(128) void k_idx(const float* __restrict__ off,
                                             const float* __restrict__ stats,
                                             const float* __restrict__ gamma,
                                             const float* __restrict__ beta,
                                             int* __restrict__ r2, int* __restrict__ r3) {
    int i = blockIdx.x, b = blockIdx.y, j = threadIdx.x;
    float tt[NCH];
#pragma unroll
    for (int ch = 0; ch < NCH; ++ch) {
        float v = off[((b * NCH + ch) << 14) + (i << 7) + j];
        v = (v - stats[ch]) * stats[NCH + ch];
        v = v * gamma[ch] + beta[ch];
        tt[ch] = (float)tanh((double)v);
    }
    float cz[9], cw[9];
    {
        const float* o = tt;
        cz[0] = 0.f;
        cz[1] = o[1];
        cz[2] = o[1] + o[2];
        cz[3] = (o[1] + o[2]) + o[3];
        cz[7] = o[7];
        cz[6] = o[7] + o[6];
        cz[5] = (o[7] + o[6]) + o[5];
        cz[4] = (cz[3] + cz[5]) * 0.5f;
        cz[8] = 0.f;
    }
    {
        const float* o = tt + 9;
        cw[0] = 0.f;
        cw[1] = o[1];
        cw[2] = o[1] + o[2];
        cw[3] = (o[1] + o[2]) + o[3];
        cw[7] = o[7];
        cw[6] = o[7] + o[6];
        cw[5] = (o[7] + o[6]) + o[5];
        cw[4] = (cw[3] + cw[5]) * 0.5f;
        cw[8] = 0.f;
    }
    const int rmax = NB * PADPIX - 1;
#pragma unroll
    for (int k = 0; k < 9; ++k) {
        int iy2 = (int)floorf((float)(i + 8 - k) + cz[k]);
        int ix2 = (int)floorf((float)(j + k) + cz[k]);
        int rr = b * 16384 + iy2 * HP + ix2;
        rr = rr < 0 ? 0 : (rr > rmax ? rmax : rr);
        r2[((b * 9 + k) << 14) + (i << 7) + j] = rr;
        int iy3 = (int)floorf((float)(i + k) + cw[k]);
        int ix3 = (int)floorf((float)(j + k) - cw[k]);
        int r3v = b * 16384 + iy3 * HP + ix3;
        r3v = r3v < 0 ? 0 : (r3v > rmax ? rmax : r3v);
        r3[((b * 9 + k) << 14) + (i << 7) + j] = r3v;
    }
}

/* main gathered strip-convs v2: block 128 thr (2 waves), tile 64 pos x 64 o,
   thread tile 4 j x 8 o. A staged in LDS [c][j] (conflict-free writes,
   contiguous b128 reads); W read DIRECTLY from global (L1-hot 36 KB) -> no
   sW staging, no second barrier, ~1 ds_read per 32 FMAs. Accumulation order
   (q outer 0..17, c inner 0..63) identical to previous rounds. */
__global__ __launch_bounds__(128) void k_main(const float* __restrict__ fpflat,
                                              const int* __restrict__ r2,
                                              const int* __restrict__ r3,
                                              const float* __restrict__ wx,
                                              const float* __restrict__ wy,
                                              const float* __restrict__ bx,
                                              const float* __restrict__ by,
                                              float* __restrict__ out) {
    __shared__ float sA[64 * 64];  /* [c][j] */
    const int b = blockIdx.z, i = blockIdx.y;
    const int j0 = blockIdx.x * 64;
    const int t = threadIdx.x;
    const int jt = t & 15;    /* j group: j0 + jt*4 .. +3 */
    const int ot = t >> 4;    /* o group: ot*8 .. +7 (ot 0..7) */
    const int sj = t >> 1;    /* staging position 0..63 */
    const int cq = t & 1;     /* staging channel half */
    float acc[4][8];
#pragma unroll
    for (int jj = 0; jj < 4; ++jj)
#pragma unroll
        for (int oo = 0; oo < 8; ++oo) acc[jj][oo] = 0.f;

    for (int q = 0; q < 18; ++q) {
        const int k = (q < 9) ? q : (q - 9);
        const int* rr = ((q < 9) ? r2 : r3) + (((b * 9 + k) << 14) + (i << 7) + j0);
        const float* wsrc = ((q < 9) ? wx : wy) + k * 4096;
        __syncthreads();
        {
            int row = rr[sj];
            const float4* src = (const float4*)(fpflat + (size_t)row * 64) + cq * 8;
#pragma unroll
            for (int u = 0; u < 8; ++u) {
                float4 v = src[u];
                int c0 = cq * 32 + u * 4;
                sA[(c0 + 0) * 64 + sj] = v.x;
                sA[(c0 + 1) * 64 + sj] = v.y;
                sA[(c0 + 2) * 64 + sj] = v.z;
                sA[(c0 + 3) * 64 + sj] = v.w;
            }
        }
        __syncthreads();
#pragma unroll 4
        for (int c = 0; c < 64; ++c) {
            float4 a4 = *(const float4*)&sA[c * 64 + jt * 4];
            float4 w0 = *(const float4*)(wsrc + c * 64 + ot * 8);
            float4 w1 = *(const float4*)(wsrc + c * 64 + ot * 8 + 4);
            const float av[4] = {a4.x, a4.y, a4.z, a4.w};
            const float wv[8] = {w0.x, w0.y, w0.z, w0.w, w1.x, w1.y, w1.z, w1.w};
#pragma unroll
            for (int jj = 0; jj < 4; ++jj)
#pragma unroll
                for (int oo = 0; oo < 8; ++oo)
                    acc[jj][oo] = fmaf(av[jj], wv[oo], acc[jj][oo]);
        }
    }
#pragma unroll
    for (int oo = 0; oo < 8; ++oo) {
        int o = ot * 8 + oo;
        float bias = bx[o] + by[o];
#pragma unroll
        for (int jj = 0; jj < 4; ++jj) {
            int j = j0 + jt * 4 + jj;
            out[(((b * NO + o) << 7) + i) * NH + j] = acc[jj][oo] + bias;
        }
    }
}

extern "C" void kernel_launch(void* const* d_in, const int* in_sizes, int n_in,
                              void* d_out, int out_size, void* d_ws, size_t ws_size,
                              hipStream_t stream) {
    const float* f     = (const float*)d_in[0];
    const float* offw  = (const float*)d_in[1];
    const float* offb  = (const float*)d_in[2];
    const float* gamma = (const float*)d_in[3];
    const float* beta  = (const float*)d_in[4];
    const float* cwx   = (const float*)d_in[5];
    const float* cbx   = (const float*)d_in[6];
    const float* cwy   = (const float*)d_in[7];
    const float* cby   = (const float*)d_in[8];
    float* ws = (float*)d_ws;
    float* fpchw  = ws + O_FPCHW;
    float* fpflat = ws + O_FPFLAT;
    float* off    = ws + O_OFF;
    float* stats  = ws + O_STATS;
    float* wx     = ws + O_WX;
    float* wy     = ws + O_WY;
    float* wr     = ws + O_WR;
    float* pp0    = ws + O_R2;       /* half-0 partials: dead before k_idx */
    int*   r2     = (int*)(ws + O_R2);
    int*   r3     = (int*)(ws + O_R3);
    float* out    = (float*)d_out;

    {
        int n4 = (2 * SZ_FP) / 4;
        k_zero<<<(n4 + 255) / 256, 256, 0, stream>>>((float4*)fpchw, n4);
    }
    k_pad<<<dim3(2, NH, NB), 256, 0, stream>>>(f, fpchw, fpflat);
    k_wt<<<(18 * 64 * 81 + 255) / 256, 256, 0, stream>>>(cwx, cwy, offw, wx, wy, wr);
    k_off<<<dim3(12, 16, NB * 2), 128, 0, stream>>>(fpchw, wr, pp0, off);
    k_stats<<<NCH, 256, 0, stream>>>(off, pp0, offb, stats);
    k_idx<<<dim3(NH, NB), 128, 0, stream>>>(off, stats, gamma, beta, r2, r3);
    k_main<<<dim3(2, NH, NB), 128, 0, stream>>>(fpflat, r2, r3, wx, wy, cbx, cby, out);
}

// Round 6
// 514.277 us; speedup vs baseline: 1.1271x; 1.1271x over previous
//
#include <hip/hip_runtime.h>
#include <math.h>

#define KK 9
#define NB 4
#define NC 64
#define NO 64
#define NH 128
#define HP 136
#define NPIX (NH*NH)     /* 16384 */
#define PADPIX (HP*HP)   /* 18496 */
#define NCH 18

/* workspace layout (float offsets) */
#define SZ_FP    (NB*NC*PADPIX)        /* 4,734,976 */
#define O_FPCHW  0
#define O_FPFLAT (O_FPCHW + SZ_FP)
#define O_OFF    (O_FPFLAT + SZ_FP)
#define SZ_OFF   (NB*NCH*NPIX)         /* 1,179,648 */
#define O_STATS  (O_OFF + SZ_OFF)
#define O_WX     (O_STATS + 64)
#define O_WY     (O_WX + KK*64*64)
#define O_R2     (O_WY + KK*64*64)
#define SZ_R     (NB*KK*NPIX)          /* 589,824 */
#define O_R3     (O_R2 + SZ_R)
/* repacked offset weights wr[c][cg6][ky][u3][12]: 64*1944 floats, after r3.
   wr is live only through k_off; r2/r3 are written later by k_idx. */
#define O_WR     (O_R3 + SZ_R)
#define WS_FLOATS (O_WR + 64*1944)     /* ~12.03M floats = 48.1 MB */

__global__ void k_zero(float4* p, int n4) {
    int id = blockIdx.x * 256 + threadIdx.x;
    if (id < n4) p[id] = make_float4(0.f, 0.f, 0.f, 0.f);
}

/* padded layouts of f: LDS-tiled so BOTH writes are coalesced */
__global__ __launch_bounds__(256) void k_pad(const float* __restrict__ f,
                                             float* __restrict__ fpchw,
                                             float* __restrict__ fpflat) {
    __shared__ float tile[64][65];   /* [c][w] */
    const int wt = blockIdx.x, h = blockIdx.y, b = blockIdx.z;
    const int w0 = wt * 64;
    const int tc = threadIdx.x >> 6;   /* 0..3 */
    const int tw = threadIdx.x & 63;
    for (int cc = tc; cc < 64; cc += 4) {
        float v = f[((b * 64 + cc) * 128 + h) * 128 + w0 + tw];
        tile[cc][tw] = v;
        fpchw[((b * 64 + cc) * HP + h + 4) * HP + w0 + tw + 4] = v;
    }
    __syncthreads();
    for (int pp = tc; pp < 64; pp += 4) {
        fpflat[(((b * HP + h + 4) * HP) + w0 + pp + 4) * 64 + tw] = tile[tw][pp];
    }
}

/* transpose main-conv weights to [k][c][o] AND repack offset weights to
   wr[c][cg][ky][u][12] with cg = co/3, u = co%3 (kx padded 9->12). */
__global__ void k_wt(const float* __restrict__ cwx, const float* __restrict__ cwy,
                     const float* __restrict__ offw,
                     float* __restrict__ wx, float* __restrict__ wy,
                     float* __restrict__ wr) {
    int id = blockIdx.x * 256 + threadIdx.x;
    if (id < KK * 64 * 64) {
        int o = id & 63;
        int c = (id >> 6) & 63;
        int k = id >> 12;
        wx[id] = cwx[(o * 64 + c) * 9 + k];
        wy[id] = cwy[(o * 64 + c) * 9 + k];
    }
    if (id < 18 * 64 * 9 * 9) {
        int kx = id % 9;
        int r = id / 9;
        int ky = r % 9; r /= 9;
        int c = r % 64;
        int co = r / 64;
        int cg = co / 3, u = co - cg * 3;
        wr[c * 1944 + cg * 324 + (ky * 3 + u) * 12 + kx] =
            offw[((co * 64 + c) * 9 + ky) * 9 + kx];
    }
}

/* offset conv, NO LDS, channel-QUARTERED for occupancy (6 waves/SIMD).
   Input via coalesced global dwordx4 (L2-hot, vmcnt pipelining), weights
   via wave-uniform s_load. 3 co x 4 j per thread over 16 channels.
   grid = (cg6*jt2, ig16, b*4+quarter) = 3072 blocks, 128 thr.
   Numerics: per-(co,c) fp32 tap chain ky->kx, double accumulation over
   ascending c within the quarter; quarters combined by fp32 atomicAdd
   (order-independent to ~2^-24 — double-level association is far inside
   the np-ref tolerance: absmax was bit-stable across r1 full-chain ->
   r4 halves). off must be pre-zeroed. */
__global__ __launch_bounds__(128) void k_off(const float* __restrict__ fpchw,
                                             const float* __restrict__ wr,
                                             float* __restrict__ off) {
    const int cg = blockIdx.x >> 1, jt = blockIdx.x & 1;   /* cg 0..5 */
    const int ig = blockIdx.y;                              /* 0..15 */
    const int b = blockIdx.z >> 2, quarter = blockIdx.z & 3;
    const int t = threadIdx.x;
    const int tr = t >> 4;            /* 0..7 */
    const int tjj = t & 15;
    const int i = ig * 8 + tr;        /* output row */
    const int j0 = jt * 64 + tjj * 4;
    const int c0 = quarter * 16, co0 = cg * 3;

    const float* frow0 = fpchw + ((size_t)(b * 64 + c0) * HP + i) * HP + j0;
    const float* wbase = wr + (size_t)c0 * 1944 + cg * 324;

    double acc[3][4];
#pragma unroll
    for (int u = 0; u < 3; ++u)
#pragma unroll
        for (int jj = 0; jj < 4; ++jj) acc[u][jj] = 0.0;

    for (int c = 0; c < 16; ++c) {
        const float* fr = frow0 + (size_t)c * PADPIX;
        const float* wc = wbase + (size_t)c * 1944;
        float p[3][4];
#pragma unroll
        for (int u = 0; u < 3; ++u)
#pragma unroll
            for (int jj = 0; jj < 4; ++jj) p[u][jj] = 0.f;
#pragma unroll
        for (int ky = 0; ky < 9; ++ky) {
            float4 va = *(const float4*)(fr + ky * HP);
            float4 vb = *(const float4*)(fr + ky * HP + 4);
            float4 vc = *(const float4*)(fr + ky * HP + 8);
            const float v[12] = {va.x, va.y, va.z, va.w, vb.x, vb.y, vb.z, vb.w,
                                 vc.x, vc.y, vc.z, vc.w};
#pragma unroll
            for (int u = 0; u < 3; ++u) {
                const float* wp = wc + (ky * 3 + u) * 12;   /* wave-uniform */
                float4 w0 = *(const float4*)(wp);
                float4 w1 = *(const float4*)(wp + 4);
                float w8 = wp[8];
                const float w[9] = {w0.x, w0.y, w0.z, w0.w,
                                    w1.x, w1.y, w1.z, w1.w, w8};
#pragma unroll
                for (int jj = 0; jj < 4; ++jj) {
                    float pu = p[u][jj];
#pragma unroll
                    for (int kx = 0; kx < 9; ++kx)
                        pu = fmaf(v[kx + jj], w[kx], pu);
                    p[u][jj] = pu;
                }
            }
        }
#pragma unroll
        for (int u = 0; u < 3; ++u)
#pragma unroll
            for (int jj = 0; jj < 4; ++jj) acc[u][jj] += (double)p[u][jj];
    }
#pragma unroll
    for (int u = 0; u < 3; ++u)
#pragma unroll
        for (int jj = 0; jj < 4; ++jj)
            atomicAdd(&off[((b * NCH + co0 + u) << 14) + (i << 7) + j0 + jj],
                      (float)acc[u][jj]);
}

/* add bias (write back to off) AND per-channel mean/rsqrt(var) in double */
__global__ __launch_bounds__(256) void k_stats(float* __restrict__ off,
                                               const float* __restrict__ offb,
                                               float* __restrict__ stats) {
    int ch = blockIdx.x, t = threadIdx.x;
    float bias = offb[ch];
    double s = 0.0, ss = 0.0;
    for (int p = t; p < NB * NPIX; p += 256) {
        int b = p >> 14, q = p & 16383;
        int x = ((b * NCH + ch) << 14) + q;
        float v = off[x] + bias;
        off[x] = v;
        s += (double)v;
        ss += (double)v * (double)v;
    }
    __shared__ double sh1[256], sh2[256];
    sh1[t] = s; sh2[t] = ss;
    __syncthreads();
    for (int st = 128; st > 0; st >>= 1) {
        if (t < st) { sh1[t] += sh1[t + st]; sh2[t] += sh2[t + st]; }
        __syncthreads();
    }
    if (t == 0) {
        double n = (double)(NB * NPIX);
        double m = sh1[0] / n;
        double var = sh2[0] / n - m * m;
        stats[ch] = (float)m;
        stats[NCH + ch] = (float)(1.0 / sqrt(var + 1e-5));
    }
}

/* BN + tanh + cum + floor -> gather row indices (reproduces base-stride bug) */
__global__ __launch_bounds__(128) void k_idx(const float* __restrict__ off,
                                             const float* __restrict__ stats,
                                             const float* __restrict__ gamma,
                                             const float* __restrict__ beta,
                                             int* __restrict__ r2, int* __restrict__ r3) {
    int i = blockIdx.x, b = blockIdx.y, j = threadIdx.x;
    float tt[NCH];
#pragma unroll
    for (int ch = 0; ch < NCH; ++ch) {
        float v = off[((b * NCH + ch) << 14) + (i << 7) + j];
        v = (v - stats[ch]) * stats[NCH + ch];
        v = v * gamma[ch] + beta[ch];
        tt[ch] = (float)tanh((double)v);
    }
    float cz[9], cw[9];
    {
        const float* o = tt;
        cz[0] = 0.f;
        cz[1] = o[1];
        cz[2] = o[1] + o[2];
        cz[3] = (o[1] + o[2]) + o[3];
        cz[7] = o[7];
        cz[6] = o[7] + o[6];
        cz[5] = (o[7] + o[6]) + o[5];
        cz[4] = (cz[3] + cz[5]) * 0.5f;
        cz[8] = 0.f;
    }
    {
        const float* o = tt + 9;
        cw[0] = 0.f;
        cw[1] = o[1];
        cw[2] = o[1] + o[2];
        cw[3] = (o[1] + o[2]) + o[3];
        cw[7] = o[7];
        cw[6] = o[7] + o[6];
        cw[5] = (o[7] + o[6]) + o[5];
        cw[4] = (cw[3] + cw[5]) * 0.5f;
        cw[8] = 0.f;
    }
    const int rmax = NB * PADPIX - 1;
#pragma unroll
    for (int k = 0; k < 9; ++k) {
        int iy2 = (int)floorf((float)(i + 8 - k) + cz[k]);
        int ix2 = (int)floorf((float)(j + k) + cz[k]);
        int rr = b * 16384 + iy2 * HP + ix2;
        rr = rr < 0 ? 0 : (rr > rmax ? rmax : rr);
        r2[((b * 9 + k) << 14) + (i << 7) + j] = rr;
        int iy3 = (int)floorf((float)(i + k) + cw[k]);
        int ix3 = (int)floorf((float)(j + k) - cw[k]);
        int r3v = b * 16384 + iy3 * HP + ix3;
        r3v = r3v < 0 ? 0 : (r3v > rmax ? rmax : r3v);
        r3[((b * 9 + k) << 14) + (i << 7) + j] = r3v;
    }
}

/* main gathered strip-convs (r4-proven): per block 64 pos x 64 out-ch,
   Kdim = 18*64, 256 thr, thread tile 4x4, A+W staged in LDS. */
__global__ __launch_bounds__(256) void k_main(const float* __restrict__ fpflat,
                                              const int* __restrict__ r2,
                                              const int* __restrict__ r3,
                                              const float* __restrict__ wx,
                                              const float* __restrict__ wy,
                                              const float* __restrict__ bx,
                                              const float* __restrict__ by,
                                              float* __restrict__ out) {
    __shared__ float sA[64 * 64];  /* [c][j] */
    __shared__ float sW[64 * 64];  /* [c][o] */
    int b = blockIdx.z, i = blockIdx.y;
    int j0 = blockIdx.x * 64;
    int t = threadIdx.x;
    int jt = t & 15;
    int ot = t >> 4;
    float acc[4][4];
#pragma unroll
    for (int a = 0; a < 4; ++a)
#pragma unroll
        for (int bb = 0; bb < 4; ++bb) acc[a][bb] = 0.f;

    int sj = t >> 2;
    int cq = t & 3;

    for (int q = 0; q < 18; ++q) {
        int k = (q < 9) ? q : (q - 9);
        const int* rr = ((q < 9) ? r2 : r3) + (((b * 9 + k) << 14) + (i << 7) + j0);
        const float* wsrc = ((q < 9) ? wx : wy) + k * 4096;
        __syncthreads();
        {
            const float4* s4 = (const float4*)wsrc;
            float4* d4 = (float4*)sW;
#pragma unroll
            for (int u = 0; u < 4; ++u) d4[t + 256 * u] = s4[t + 256 * u];
        }
        {
            int row = rr[sj];
            const float* src = fpflat + (size_t)row * 64;
#pragma unroll
            for (int u = 0; u < 4; ++u) {
                int c0 = cq * 16 + u * 4;
                float4 v = *(const float4*)(src + c0);
                sA[(c0 + 0) * 64 + sj] = v.x;
                sA[(c0 + 1) * 64 + sj] = v.y;
                sA[(c0 + 2) * 64 + sj] = v.z;
                sA[(c0 + 3) * 64 + sj] = v.w;
            }
        }
        __syncthreads();
#pragma unroll 4
        for (int c = 0; c < 64; ++c) {
            float4 a4 = *(const float4*)&sA[c * 64 + jt * 4];
            float4 w4 = *(const float4*)&sW[c * 64 + ot * 4];
            const float av[4] = {a4.x, a4.y, a4.z, a4.w};
            const float wv[4] = {w4.x, w4.y, w4.z, w4.w};
#pragma unroll
            for (int jj = 0; jj < 4; ++jj)
#pragma unroll
                for (int oo = 0; oo < 4; ++oo)
                    acc[jj][oo] = fmaf(av[jj], wv[oo], acc[jj][oo]);
        }
    }
#pragma unroll
    for (int oo = 0; oo < 4; ++oo) {
        int o = ot * 4 + oo;
        float bias = bx[o] + by[o];
#pragma unroll
        for (int jj = 0; jj < 4; ++jj) {
            int j = j0 + jt * 4 + jj;
            out[(((b * NO + o) << 7) + i) * NH + j] = acc[jj][oo] + bias;
        }
    }
}

extern "C" void kernel_launch(void* const* d_in, const int* in_sizes, int n_in,
                              void* d_out, int out_size, void* d_ws, size_t ws_size,
                              hipStream_t stream) {
    const float* f     = (const float*)d_in[0];
    const float* offw  = (const float*)d_in[1];
    const float* offb  = (const float*)d_in[2];
    const float* gamma = (const float*)d_in[3];
    const float* beta  = (const float*)d_in[4];
    const float* cwx   = (const float*)d_in[5];
    const float* cbx   = (const float*)d_in[6];
    const float* cwy   = (const float*)d_in[7];
    const float* cby   = (const float*)d_in[8];
    float* ws = (float*)d_ws;
    float* fpchw  = ws + O_FPCHW;
    float* fpflat = ws + O_FPFLAT;
    float* off    = ws + O_OFF;
    float* stats  = ws + O_STATS;
    float* wx     = ws + O_WX;
    float* wy     = ws + O_WY;
    float* wr     = ws + O_WR;
    int*   r2     = (int*)(ws + O_R2);
    int*   r3     = (int*)(ws + O_R3);
    float* out    = (float*)d_out;

    /* zero fpchw + fpflat + off (contiguous) — off must be 0 for atomics */
    {
        int n4 = (2 * SZ_FP + SZ_OFF) / 4;
        k_zero<<<(n4 + 255) / 256, 256, 0, stream>>>((float4*)fpchw, n4);
    }
    k_pad<<<dim3(2, NH, NB), 256, 0, stream>>>(f, fpchw, fpflat);
    k_wt<<<(18 * 64 * 81 + 255) / 256, 256, 0, stream>>>(cwx, cwy, offw, wx, wy, wr);
    k_off<<<dim3(12, 16, NB * 4), 128, 0, stream>>>(fpchw, wr, off);
    k_stats<<<NCH, 256, 0, stream>>>(off, offb, stats);
    k_idx<<<dim3(NH, NB), 128, 0, stream>>>(off, stats, gamma, beta, r2, r3);
    k_main<<<dim3(2, NH, NB), 256, 0, stream>>>(fpflat, r2, r3, wx, wy, cbx, cby, out);
}

// Round 7
// 408.788 us; speedup vs baseline: 1.4180x; 1.2581x over previous
//
#include <hip/hip_runtime.h>
#include <math.h>

#define KK 9
#define NB 4
#define NC 64
#define NO 64
#define NH 128
#define HP 136
#define NPIX (NH*NH)     /* 16384 */
#define PADPIX (HP*HP)   /* 18496 */
#define NCH 18

typedef short bf16x8 __attribute__((ext_vector_type(8)));
typedef float f32x4 __attribute__((ext_vector_type(4)));

/* workspace layout (float offsets) */
#define SZ_FP    (NB*NC*PADPIX)        /* 4,734,976 */
#define O_FPCHW  0
#define O_FPF16  (O_FPCHW + SZ_FP)              /* bf16 padded-flat: SZ_FP shorts */
#define SZ_FPF16F (SZ_FP/2)
#define O_OFF    (O_FPF16 + SZ_FPF16F)
#define SZ_OFF   (NB*NCH*NPIX)         /* 1,179,648 */
#define O_STATS  (O_OFF + SZ_OFF)
#define O_WXB    (O_STATS + 64)                 /* bf16 [k][o][c]: 36,864 shorts */
#define O_WYB    (O_WXB + KK*64*64/2)
#define O_R2     (O_WYB + KK*64*64/2)
#define SZ_R     (NB*KK*NPIX)          /* 589,824 */
#define O_R3     (O_R2 + SZ_R)
#define O_WR     (O_R3 + SZ_R)        /* fp32 repacked offset weights */
#define WS_FLOATS (O_WR + 64*1944)    /* ~9.62M floats = 38.5 MB */

__device__ inline unsigned short f2bf(float x) {   /* RTNE fp32->bf16 */
    unsigned u = __float_as_uint(x);
    u += 0x7FFFu + ((u >> 16) & 1u);
    return (unsigned short)(u >> 16);
}

__global__ void k_zero(float4* p, int n4) {
    int id = blockIdx.x * 256 + threadIdx.x;
    if (id < n4) p[id] = make_float4(0.f, 0.f, 0.f, 0.f);
}

/* padded layouts of f: fp32 CHW (for k_off) + bf16 flat HWC (for k_main) */
__global__ __launch_bounds__(256) void k_pad(const float* __restrict__ f,
                                             float* __restrict__ fpchw,
                                             unsigned short* __restrict__ fpf16) {
    __shared__ float tile[64][65];   /* [c][w] */
    const int wt = blockIdx.x, h = blockIdx.y, b = blockIdx.z;
    const int w0 = wt * 64;
    const int tc = threadIdx.x >> 6;   /* 0..3 */
    const int tw = threadIdx.x & 63;
    for (int cc = tc; cc < 64; cc += 4) {
        float v = f[((b * 64 + cc) * 128 + h) * 128 + w0 + tw];
        tile[cc][tw] = v;
        fpchw[((b * 64 + cc) * HP + h + 4) * HP + w0 + tw + 4] = v;
    }
    __syncthreads();
    for (int pp = tc; pp < 64; pp += 4) {
        fpf16[(((b * HP + h + 4) * HP) + w0 + pp + 4) * 64 + tw] =
            f2bf(tile[tw][pp]);
    }
}

/* main-conv weights -> bf16 [k][o][c]; offset weights -> wr[c][cg][ky][u][12] */
__global__ void k_wt(const float* __restrict__ cwx, const float* __restrict__ cwy,
                     const float* __restrict__ offw,
                     unsigned short* __restrict__ wxb,
                     unsigned short* __restrict__ wyb,
                     float* __restrict__ wr) {
    int id = blockIdx.x * 256 + threadIdx.x;
    if (id < KK * 64 * 64) {
        int o = (id >> 6) & 63;
        int c = id & 63;
        int k = id >> 12;
        wxb[id] = f2bf(cwx[(o * 64 + c) * 9 + k]);
        wyb[id] = f2bf(cwy[(o * 64 + c) * 9 + k]);
    }
    if (id < 18 * 64 * 9 * 9) {
        int kx = id % 9;
        int r = id / 9;
        int ky = r % 9; r /= 9;
        int c = r % 64;
        int co = r / 64;
        int cg = co / 3, u = co - cg * 3;
        wr[c * 1944 + cg * 324 + (ky * 3 + u) * 12 + kx] =
            offw[((co * 64 + c) * 9 + ky) * 9 + kx];
    }
}

/* offset conv (unchanged from r6): NO LDS, channel-quartered, fp32 tap chain
   ky->kx per (co,c), double accumulation over c, quarters via atomicAdd. */
__global__ __launch_bounds__(128) void k_off(const float* __restrict__ fpchw,
                                             const float* __restrict__ wr,
                                             float* __restrict__ off) {
    const int cg = blockIdx.x >> 1, jt = blockIdx.x & 1;
    const int ig = blockIdx.y;
    const int b = blockIdx.z >> 2, quarter = blockIdx.z & 3;
    const int t = threadIdx.x;
    const int tr = t >> 4;
    const int tjj = t & 15;
    const int i = ig * 8 + tr;
    const int j0 = jt * 64 + tjj * 4;
    const int c0 = quarter * 16, co0 = cg * 3;

    const float* frow0 = fpchw + ((size_t)(b * 64 + c0) * HP + i) * HP + j0;
    const float* wbase = wr + (size_t)c0 * 1944 + cg * 324;

    double acc[3][4];
#pragma unroll
    for (int u = 0; u < 3; ++u)
#pragma unroll
        for (int jj = 0; jj < 4; ++jj) acc[u][jj] = 0.0;

    for (int c = 0; c < 16; ++c) {
        const float* fr = frow0 + (size_t)c * PADPIX;
        const float* wc = wbase + (size_t)c * 1944;
        float p[3][4];
#pragma unroll
        for (int u = 0; u < 3; ++u)
#pragma unroll
            for (int jj = 0; jj < 4; ++jj) p[u][jj] = 0.f;
#pragma unroll
        for (int ky = 0; ky < 9; ++ky) {
            float4 va = *(const float4*)(fr + ky * HP);
            float4 vb = *(const float4*)(fr + ky * HP + 4);
            float4 vc = *(const float4*)(fr + ky * HP + 8);
            const float v[12] = {va.x, va.y, va.z, va.w, vb.x, vb.y, vb.z, vb.w,
                                 vc.x, vc.y, vc.z, vc.w};
#pragma unroll
            for (int u = 0; u < 3; ++u) {
                const float* wp = wc + (ky * 3 + u) * 12;
                float4 w0 = *(const float4*)(wp);
                float4 w1 = *(const float4*)(wp + 4);
                float w8 = wp[8];
                const float w[9] = {w0.x, w0.y, w0.z, w0.w,
                                    w1.x, w1.y, w1.z, w1.w, w8};
#pragma unroll
                for (int jj = 0; jj < 4; ++jj) {
                    float pu = p[u][jj];
#pragma unroll
                    for (int kx = 0; kx < 9; ++kx)
                        pu = fmaf(v[kx + jj], w[kx], pu);
                    p[u][jj] = pu;
                }
            }
        }
#pragma unroll
        for (int u = 0; u < 3; ++u)
#pragma unroll
            for (int jj = 0; jj < 4; ++jj) acc[u][jj] += (double)p[u][jj];
    }
#pragma unroll
    for (int u = 0; u < 3; ++u)
#pragma unroll
        for (int jj = 0; jj < 4; ++jj)
            atomicAdd(&off[((b * NCH + co0 + u) << 14) + (i << 7) + j0 + jj],
                      (float)acc[u][jj]);
}

/* add bias (write back) AND per-channel mean/rsqrt(var) in double */
__global__ __launch_bounds__(256) void k_stats(float* __restrict__ off,
                                               const float* __restrict__ offb,
                                               float* __restrict__ stats) {
    int ch = blockIdx.x, t = threadIdx.x;
    float bias = offb[ch];
    double s = 0.0, ss = 0.0;
    for (int p = t; p < NB * NPIX; p += 256) {
        int b = p >> 14, q = p & 16383;
        int x = ((b * NCH + ch) << 14) + q;
        float v = off[x] + bias;
        off[x] = v;
        s += (double)v;
        ss += (double)v * (double)v;
    }
    __shared__ double sh1[256], sh2[256];
    sh1[t] = s; sh2[t] = ss;
    __syncthreads();
    for (int st = 128; st > 0; st >>= 1) {
        if (t < st) { sh1[t] += sh1[t + st]; sh2[t] += sh2[t + st]; }
        __syncthreads();
    }
    if (t == 0) {
        double n = (double)(NB * NPIX);
        double m = sh1[0] / n;
        double var = sh2[0] / n - m * m;
        stats[ch] = (float)m;
        stats[NCH + ch] = (float)(1.0 / sqrt(var + 1e-5));
    }
}

/* BN + tanh + cum + floor -> gather row indices (reproduces base-stride bug) */
__global__ __launch_bounds__(128) void k_idx(const float* __restrict__ off,
                                             const float* __restrict__ stats,
                                             const float* __restrict__ gamma,
                                             const float* __restrict__ beta,
                                             int* __restrict__ r2, int* __restrict__ r3) {
    int i = blockIdx.x, b = blockIdx.y, j = threadIdx.x;
    float tt[NCH];
#pragma unroll
    for (int ch = 0; ch < NCH; ++ch) {
        float v = off[((b * NCH + ch) << 14) + (i << 7) + j];
        v = (v - stats[ch]) * stats[NCH + ch];
        v = v * gamma[ch] + beta[ch];
        tt[ch] = (float)tanh((double)v);
    }
    float cz[9], cw[9];
    {
        const float* o = tt;
        cz[0] = 0.f;
        cz[1] = o[1];
        cz[2] = o[1] + o[2];
        cz[3] = (o[1] + o[2]) + o[3];
        cz[7] = o[7];
        cz[6] = o[7] + o[6];
        cz[5] = (o[7] + o[6]) + o[5];
        cz[4] = (cz[3] + cz[5]) * 0.5f;
        cz[8] = 0.f;
    }
    {
        const float* o = tt + 9;
        cw[0] = 0.f;
        cw[1] = o[1];
        cw[2] = o[1] + o[2];
        cw[3] = (o[1] + o[2]) + o[3];
        cw[7] = o[7];
        cw[6] = o[7] + o[6];
        cw[5] = (o[7] + o[6]) + o[5];
        cw[4] = (cw[3] + cw[5]) * 0.5f;
        cw[8] = 0.f;
    }
    const int rmax = NB * PADPIX - 1;
#pragma unroll
    for (int k = 0; k < 9; ++k) {
        int iy2 = (int)floorf((float)(i + 8 - k) + cz[k]);
        int ix2 = (int)floorf((float)(j + k) + cz[k]);
        int rr = b * 16384 + iy2 * HP + ix2;
        rr = rr < 0 ? 0 : (rr > rmax ? rmax : rr);
        r2[((b * 9 + k) << 14) + (i << 7) + j] = rr;
        int iy3 = (int)floorf((float)(i + k) + cw[k]);
        int ix3 = (int)floorf((float)(j + k) - cw[k]);
        int r3v = b * 16384 + iy3 * HP + ix3;
        r3v = r3v < 0 ? 0 : (r3v > rmax ? rmax : r3v);
        r3[((b * 9 + k) << 14) + (i << 7) + j] = r3v;
    }
}

/* main gathered strip-convs via MFMA bf16 16x16x32.
   Block 256 thr (4 waves) = 64 pos x 64 o tile; K = 18 taps x 64 ch.
   Per q: stage gathered bf16 A rows [j][c] + W slice [o][c] in LDS (rows
   padded to 72 shorts); each wave owns j-tile = wave_id, loops 4 o-tiles,
   2 K-chunks of 32 -> 8 MFMA/wave/q. Verified layouts (guide §3/m120):
   A[m=lane&15][k=quad*8+e], B[k=quad*8+e][n=lane&15], D col=lane&15,
   row=quad*4+reg. Epilogue transposes via LDS for coalesced stores. */
__global__ __launch_bounds__(256) void k_main(const unsigned short* __restrict__ fpf16,
                                              const int* __restrict__ r2,
                                              const int* __restrict__ r3,
                                              const unsigned short* __restrict__ wxb,
                                              const unsigned short* __restrict__ wyb,
                                              const float* __restrict__ bx,
                                              const float* __restrict__ by,
                                              float* __restrict__ out) {
    __shared__ __align__(16) unsigned char smem[2 * 64 * 72 * 2 > 64 * 68 * 4
                                                ? 2 * 64 * 72 * 2 : 64 * 68 * 4];
    unsigned short* sA = (unsigned short*)smem;            /* [64][72] */
    unsigned short* sW = (unsigned short*)smem + 64 * 72;  /* [64][72] */

    const int b = blockIdx.z, i = blockIdx.y, j0 = blockIdx.x * 64;
    const int t = threadIdx.x;
    const int wv = t >> 6, lane = t & 63;
    const int m = lane & 15, quad = lane >> 4;
    const int sj = t >> 2, q4 = t & 3;    /* staging: row, 16-short chunk */

    f32x4 acc[4];
#pragma unroll
    for (int ot = 0; ot < 4; ++ot) acc[ot] = (f32x4){0.f, 0.f, 0.f, 0.f};

    for (int q = 0; q < 18; ++q) {
        const int k = (q < 9) ? q : (q - 9);
        const int* rr = ((q < 9) ? r2 : r3) + (((b * 9 + k) << 14) + (i << 7) + j0);
        const unsigned short* wsrc = ((q < 9) ? wxb : wyb) + k * 4096;
        __syncthreads();
        {   /* stage A: gathered row sj, chunk q4 (16 shorts = 32 B) */
            int row = rr[sj];
            const uint4* src = (const uint4*)(fpf16 + (size_t)row * 64 + q4 * 16);
            uint4 v0 = src[0], v1 = src[1];
            *(uint4*)(sA + sj * 72 + q4 * 16) = v0;
            *(uint4*)(sA + sj * 72 + q4 * 16 + 8) = v1;
            /* stage W: o = sj, chunk q4 */
            const uint4* ws = (const uint4*)(wsrc + sj * 64 + q4 * 16);
            uint4 w0 = ws[0], w1 = ws[1];
            *(uint4*)(sW + sj * 72 + q4 * 16) = w0;
            *(uint4*)(sW + sj * 72 + q4 * 16 + 8) = w1;
        }
        __syncthreads();
        bf16x8 a0 = *(const bf16x8*)(sA + (wv * 16 + m) * 72 + quad * 8);
        bf16x8 a1 = *(const bf16x8*)(sA + (wv * 16 + m) * 72 + 32 + quad * 8);
#pragma unroll
        for (int ot = 0; ot < 4; ++ot) {
            bf16x8 b0 = *(const bf16x8*)(sW + (ot * 16 + m) * 72 + quad * 8);
            bf16x8 b1 = *(const bf16x8*)(sW + (ot * 16 + m) * 72 + 32 + quad * 8);
            acc[ot] = __builtin_amdgcn_mfma_f32_16x16x32_bf16(a0, b0, acc[ot], 0, 0, 0);
            acc[ot] = __builtin_amdgcn_mfma_f32_16x16x32_bf16(a1, b1, acc[ot], 0, 0, 0);
        }
    }
    /* epilogue: scatter D into LDS [o][j] (rows padded to 68 f), then
       coalesced global stores with bias */
    __syncthreads();
    float* sD = (float*)smem;
#pragma unroll
    for (int ot = 0; ot < 4; ++ot) {
        int o = ot * 16 + m;
        int jr = wv * 16 + quad * 4;
#pragma unroll
        for (int r = 0; r < 4; ++r)
            sD[o * 68 + jr + r] = acc[ot][r];
    }
    __syncthreads();
    {
        int o = t >> 2, jq = t & 3;
        float bias = bx[o] + by[o];
        float* dst = out + (((b * NO + o) << 7) + i) * NH + j0 + jq * 16;
        const float* srcrow = sD + o * 68 + jq * 16;
#pragma unroll
        for (int u = 0; u < 4; ++u) {
            float4 v = *(const float4*)(srcrow + u * 4);
            v.x += bias; v.y += bias; v.z += bias; v.w += bias;
            *(float4*)(dst + u * 4) = v;
        }
    }
}

extern "C" void kernel_launch(void* const* d_in, const int* in_sizes, int n_in,
                              void* d_out, int out_size, void* d_ws, size_t ws_size,
                              hipStream_t stream) {
    const float* f     = (const float*)d_in[0];
    const float* offw  = (const float*)d_in[1];
    const float* offb  = (const float*)d_in[2];
    const float* gamma = (const float*)d_in[3];
    const float* beta  = (const float*)d_in[4];
    const float* cwx   = (const float*)d_in[5];
    const float* cbx   = (const float*)d_in[6];
    const float* cwy   = (const float*)d_in[7];
    const float* cby   = (const float*)d_in[8];
    float* ws = (float*)d_ws;
    float* fpchw  = ws + O_FPCHW;
    unsigned short* fpf16 = (unsigned short*)(ws + O_FPF16);
    float* off    = ws + O_OFF;
    float* stats  = ws + O_STATS;
    unsigned short* wxb = (unsigned short*)(ws + O_WXB);
    unsigned short* wyb = (unsigned short*)(ws + O_WYB);
    float* wr     = ws + O_WR;
    int*   r2     = (int*)(ws + O_R2);
    int*   r3     = (int*)(ws + O_R3);
    float* out    = (float*)d_out;

    /* zero fpchw + fpf16 + off (contiguous): padding must be 0, off for atomics */
    {
        int n4 = (SZ_FP + SZ_FPF16F + SZ_OFF) / 4;
        k_zero<<<(n4 + 255) / 256, 256, 0, stream>>>((float4*)fpchw, n4);
    }
    k_pad<<<dim3(2, NH, NB), 256, 0, stream>>>(f, fpchw, fpf16);
    k_wt<<<(18 * 64 * 81 + 255) / 256, 256, 0, stream>>>(cwx, cwy, offw, wxb, wyb, wr);
    k_off<<<dim3(12, 16, NB * 4), 128, 0, stream>>>(fpchw, wr, off);
    k_stats<<<NCH, 256, 0, stream>>>(off, offb, stats);
    k_idx<<<dim3(NH, NB), 128, 0, stream>>>(off, stats, gamma, beta, r2, r3);
    k_main<<<dim3(2, NH, NB), 256, 0, stream>>>(fpf16, r2, r3, wxb, wyb, cbx, cby, out);
}